// Round 4
// baseline (128.746 us; speedup 1.0000x reference)
//
#include <hip/hip_runtime.h>
#include <float.h>

#define N_BINS 20
#define C 128

typedef float f32x4 __attribute__((ext_vector_type(4)));

// ---------------------------------------------------------------------------
// Kernel 1: zero the 40-float accumulator region of the workspace.
// (Harness poisons d_ws once and never re-poisons between timed replays.)
// ---------------------------------------------------------------------------
__global__ void ece_init(float* __restrict__ ws) {
    int t = threadIdx.x;
    if (t < 2 * N_BINS) ws[t] = 0.0f;
}

// ---------------------------------------------------------------------------
// Kernel 2: per-row max/argmax + binned accumulation.
//
// Layout: 4 lanes per row; each lane loads 8x float4 (128 B) of its row:
//   lane l -> row (base + (l>>2)), float4 #((l&3) + 4*j), j=0..7
// Wave-iter covers 16 rows (8 KB): 8 independent dwordx4 loads in flight per
// lane. Per instruction the wave touches 16 rows x 64-B aligned
// fully-consumed segments -> coalesced. Loads are nontemporal (nt) --
// pure stream, no reuse, keep it out of L2.
//
// In-lane reduction is tree-shaped (depth 5): pairwise fmaxf tree for the
// max, then an equality-match min-index tree for first-occurrence argmax
// (bit-exact compare against the fmaxf result). Cross-lane: 2 xor-shuffle
// steps within each 4-lane group.
// ---------------------------------------------------------------------------
__global__ __launch_bounds__(256) void ece_main(const float* __restrict__ outs,
                                                const int* __restrict__ labels,
                                                float* __restrict__ ws,
                                                int n_rows, int n_waves) {
    __shared__ float s_conf[N_BINS];
    __shared__ float s_acc[N_BINS];

    const int tid = threadIdx.x;
    if (tid < N_BINS) {
        s_conf[tid] = 0.0f;
        s_acc[tid]  = 0.0f;
    }
    __syncthreads();

    const int lane = tid & 63;
    const int sub  = lane & 3;    // chunk-column within the row
    const int rsub = lane >> 2;   // which of the wave's 16 rows
    const int gwave = blockIdx.x * 4 + (tid >> 6);

    const f32x4* __restrict__ outs4 = reinterpret_cast<const f32x4*>(outs);

    for (int rowBase = gwave * 16; rowBase < n_rows; rowBase += n_waves * 16) {
        const int row = rowBase + rsub;
        const bool live = (row < n_rows);

        // Prefetch label early (leader lanes only); hides under loads+reduce.
        int lab = -1;
        if (sub == 0 && live) lab = labels[row];

        float bestVal = -FLT_MAX;
        int   bestIdx = 0x7fffffff;

        if (live) {
            const f32x4* p = outs4 + (size_t)row * (C / 4) + sub;
            f32x4 v[8];
            #pragma unroll
            for (int j = 0; j < 8; ++j)
                v[j] = __builtin_nontemporal_load(p + j * 4);

            float va[32];
            #pragma unroll
            for (int j = 0; j < 8; ++j) {
                va[4 * j + 0] = v[j].x;
                va[4 * j + 1] = v[j].y;
                va[4 * j + 2] = v[j].z;
                va[4 * j + 3] = v[j].w;
            }

            // --- pairwise max tree (depth 5, 31 ops) ---
            float mx[16];
            #pragma unroll
            for (int i = 0; i < 16; ++i) mx[i] = fmaxf(va[i], va[i + 16]);
            #pragma unroll
            for (int s = 8; s >= 1; s >>= 1)
                #pragma unroll
                for (int i = 0; i < s; ++i) mx[i] = fmaxf(mx[i], mx[i + s]);
            bestVal = mx[0];

            // --- first-occurrence index: min over {elem idx : va==max} ---
            // local i = 4*j + c  ->  row-element index = sub*4 + j*16 + c
            int ix[16];
            #pragma unroll
            for (int i = 0; i < 16; ++i) {
                const int e0 = sub * 4 + ((i) >> 2) * 16 + ((i) & 3);
                const int e1 = sub * 4 + ((i + 16) >> 2) * 16 + ((i + 16) & 3);
                const int c0 = (va[i]      == bestVal) ? e0 : 0x7fffffff;
                const int c1 = (va[i + 16] == bestVal) ? e1 : 0x7fffffff;
                ix[i] = min(c0, c1);
            }
            #pragma unroll
            for (int s = 8; s >= 1; s >>= 1)
                #pragma unroll
                for (int i = 0; i < s; ++i) ix[i] = min(ix[i], ix[i + s]);
            bestIdx = ix[0];
        }

        // 2-step butterfly within each 4-lane group. Lowest-index tiebreak.
        #pragma unroll
        for (int m = 1; m <= 2; m <<= 1) {
            const float ov = __shfl_xor(bestVal, m);
            const int   oi = __shfl_xor(bestIdx, m);
            if (ov > bestVal || (ov == bestVal && oi < bestIdx)) {
                bestVal = ov;
                bestIdx = oi;
            }
        }

        if (sub == 0 && live) {
            // bin = clip(ceil(conf*20) - 1, 0, 19): same f32 arithmetic as ref.
            int bin = (int)ceilf(bestVal * (float)N_BINS) - 1;
            bin = min(max(bin, 0), N_BINS - 1);
            atomicAdd(&s_conf[bin], bestVal);
            atomicAdd(&s_acc[bin], (bestIdx == lab) ? 1.0f : 0.0f);
        }
    }

    __syncthreads();
    if (tid < N_BINS) {
        atomicAdd(&ws[tid], s_conf[tid]);
    } else if (tid < 2 * N_BINS) {
        atomicAdd(&ws[tid], s_acc[tid - N_BINS]);
    }
}

// ---------------------------------------------------------------------------
// Kernel 3: ece = sum_b |sum_conf_b - sum_acc_b| / N
// ---------------------------------------------------------------------------
__global__ void ece_final(const float* __restrict__ ws,
                          float* __restrict__ out, float inv_n) {
    const int t = threadIdx.x;   // 64 threads
    float d = (t < N_BINS) ? fabsf(ws[t] - ws[t + N_BINS]) : 0.0f;
    #pragma unroll
    for (int m = 1; m <= 32; m <<= 1) d += __shfl_xor(d, m);
    if (t == 0) out[0] = d * inv_n;
}

extern "C" void kernel_launch(void* const* d_in, const int* in_sizes, int n_in,
                              void* d_out, int out_size, void* d_ws, size_t ws_size,
                              hipStream_t stream) {
    const float* outs   = (const float*)d_in[0];
    const int*   labels = (const int*)d_in[1];
    float*       out    = (float*)d_out;
    float*       ws     = (float*)d_ws;

    const int n_rows  = in_sizes[1];   // labels count == N
    const int blocks  = 2048;          // 8 blocks/CU
    const int n_waves = blocks * 4;

    hipLaunchKernelGGL(ece_init, dim3(1), dim3(64), 0, stream, ws);
    hipLaunchKernelGGL(ece_main, dim3(blocks), dim3(256), 0, stream,
                       outs, labels, ws, n_rows, n_waves);
    hipLaunchKernelGGL(ece_final, dim3(1), dim3(64), 0, stream,
                       ws, out, 1.0f / (float)n_rows);
}

// Round 5
// 121.577 us; speedup vs baseline: 1.0590x; 1.0590x over previous
//
#include <hip/hip_runtime.h>
#include <float.h>

#define N_BINS 20
#define C 128

typedef float f32x4 __attribute__((ext_vector_type(4)));

// ---------------------------------------------------------------------------
// Kernel 1: zero the 40-float accumulator region of the workspace.
// (Harness poisons d_ws once and never re-poisons between timed replays.)
// ---------------------------------------------------------------------------
__global__ void ece_init(float* __restrict__ ws) {
    int t = threadIdx.x;
    if (t < 2 * N_BINS) ws[t] = 0.0f;
}

// ---------------------------------------------------------------------------
// Kernel 2: per-row max/argmax + binned accumulation.
//
// Layout (R2-proven): 8 lanes per row, each lane loads 4x float4:
//   lane l -> row (base + (l>>3)), float4 #((l&7) + 8*j), j=0..3
// Per load instruction the wave covers 8 rows x one full 128-B cache line.
//
// NEW: explicit register double-buffer across grid-stride iterations --
// iteration i+1's 4 loads (+ label) are issued BEFORE iteration i's scan,
// so HBM latency hides under compute instead of serializing with it.
// VGPR stays ~64 (v[4]+nv[4]=32 data regs) -> full 32 waves/CU occupancy.
// ---------------------------------------------------------------------------
__global__ __launch_bounds__(256) void ece_main(const float* __restrict__ outs,
                                                const int* __restrict__ labels,
                                                float* __restrict__ ws,
                                                int n_rows, int n_waves) {
    __shared__ float s_conf[N_BINS];
    __shared__ float s_acc[N_BINS];

    const int tid = threadIdx.x;
    if (tid < N_BINS) {
        s_conf[tid] = 0.0f;
        s_acc[tid]  = 0.0f;
    }
    __syncthreads();

    const int lane = tid & 63;
    const int sub  = lane & 7;    // chunk-column within the row
    const int rsub = lane >> 3;   // which of the wave's 8 rows
    const int gwave = blockIdx.x * 4 + (tid >> 6);
    const int rstride = n_waves * 8;

    const f32x4* __restrict__ outs4 = reinterpret_cast<const f32x4*>(outs);

    int  row  = gwave * 8 + rsub;
    bool live = (row < n_rows);

    // ---- prologue: load first tile ----
    f32x4 v[4];
    int lab = -1;
    if (live) {
        const f32x4* p = outs4 + (size_t)row * (C / 4) + sub;
        #pragma unroll
        for (int j = 0; j < 4; ++j) v[j] = p[j * 8];
        if (sub == 0) lab = labels[row];
    }

    while (live) {
        // ---- issue next tile's loads before scanning current ----
        const int  nrow  = row + rstride;
        const bool nlive = (nrow < n_rows);
        f32x4 nv[4];
        int nlab = -1;
        if (nlive) {
            const f32x4* np = outs4 + (size_t)nrow * (C / 4) + sub;
            #pragma unroll
            for (int j = 0; j < 4; ++j) nv[j] = np[j * 8];
            if (sub == 0) nlab = labels[nrow];
        }

        // ---- scan current tile (strict '>' serial scan, first-occurrence) ----
        // element index of v[j].c within the row = 4*sub + 32*j + c
        float bestVal = v[0].x;
        int   bestIdx = 4 * sub;
        {
            const int b0 = 4 * sub;
            #pragma unroll
            for (int j = 0; j < 4; ++j) {
                const int b = b0 + 32 * j;
                if (j > 0 && v[j].x > bestVal) { bestVal = v[j].x; bestIdx = b; }
                if (v[j].y > bestVal) { bestVal = v[j].y; bestIdx = b + 1; }
                if (v[j].z > bestVal) { bestVal = v[j].z; bestIdx = b + 2; }
                if (v[j].w > bestVal) { bestVal = v[j].w; bestIdx = b + 3; }
            }
        }

        // ---- 3-step butterfly within each 8-lane group ----
        #pragma unroll
        for (int m = 1; m <= 4; m <<= 1) {
            const float ov = __shfl_xor(bestVal, m);
            const int   oi = __shfl_xor(bestIdx, m);
            if (ov > bestVal || (ov == bestVal && oi < bestIdx)) {
                bestVal = ov;
                bestIdx = oi;
            }
        }

        if (sub == 0) {
            // bin = clip(ceil(conf*20) - 1, 0, 19): same f32 arithmetic as ref.
            int bin = (int)ceilf(bestVal * (float)N_BINS) - 1;
            bin = min(max(bin, 0), N_BINS - 1);
            atomicAdd(&s_conf[bin], bestVal);
            atomicAdd(&s_acc[bin], (bestIdx == lab) ? 1.0f : 0.0f);
        }

        // ---- rotate double-buffer ----
        row  = nrow;
        live = nlive;
        lab  = nlab;
        #pragma unroll
        for (int j = 0; j < 4; ++j) v[j] = nv[j];
    }

    __syncthreads();
    if (tid < N_BINS) {
        atomicAdd(&ws[tid], s_conf[tid]);
    } else if (tid < 2 * N_BINS) {
        atomicAdd(&ws[tid], s_acc[tid - N_BINS]);
    }
}

// ---------------------------------------------------------------------------
// Kernel 3: ece = sum_b |sum_conf_b - sum_acc_b| / N
// ---------------------------------------------------------------------------
__global__ void ece_final(const float* __restrict__ ws,
                          float* __restrict__ out, float inv_n) {
    const int t = threadIdx.x;   // 64 threads
    float d = (t < N_BINS) ? fabsf(ws[t] - ws[t + N_BINS]) : 0.0f;
    #pragma unroll
    for (int m = 1; m <= 32; m <<= 1) d += __shfl_xor(d, m);
    if (t == 0) out[0] = d * inv_n;
}

extern "C" void kernel_launch(void* const* d_in, const int* in_sizes, int n_in,
                              void* d_out, int out_size, void* d_ws, size_t ws_size,
                              hipStream_t stream) {
    const float* outs   = (const float*)d_in[0];
    const int*   labels = (const int*)d_in[1];
    float*       out    = (float*)d_out;
    float*       ws     = (float*)d_ws;

    const int n_rows  = in_sizes[1];   // labels count == N
    const int blocks  = 2048;          // 8 blocks/CU -> 32 waves/CU
    const int n_waves = blocks * 4;

    hipLaunchKernelGGL(ece_init, dim3(1), dim3(64), 0, stream, ws);
    hipLaunchKernelGGL(ece_main, dim3(blocks), dim3(256), 0, stream,
                       outs, labels, ws, n_rows, n_waves);
    hipLaunchKernelGGL(ece_final, dim3(1), dim3(64), 0, stream,
                       ws, out, 1.0f / (float)n_rows);
}

// Round 6
// 105.989 us; speedup vs baseline: 1.2147x; 1.1471x over previous
//
#include <hip/hip_runtime.h>
#include <float.h>

#define N_BINS 20
#define C 128
#define NVAL (2 * N_BINS)   // 20 conf-sums + 20 acc-sums

typedef float f32x4 __attribute__((ext_vector_type(4)));

// ---------------------------------------------------------------------------
// Kernel 0 (fallback mode only): zero the shared slot array.
// ---------------------------------------------------------------------------
__global__ void ece_init(float* __restrict__ slots, int total) {
    int t = blockIdx.x * blockDim.x + threadIdx.x;
    if (t < total) slots[t] = 0.0f;
}

// ---------------------------------------------------------------------------
// Kernel 1: per-row max/argmax + per-block partial histogram.
//
// Layout (R2-proven): 8 lanes per row, each lane loads 4x float4; per load
// instruction the wave covers 8 rows x one full 128-B line. 3-step butterfly
// within 8-lane groups, lowest-index tiebreak (first-occurrence argmax).
//
// NEW vs R5: NO cross-block global atomics. Each block writes its 40-float
// partial histogram to a PRIVATE slot in d_ws (plain stores, fully
// overwritten every call -> no init, no 2048-deep atomic serialization tail).
// Slot layout is [value j][slot s] so the reduction kernel reads coalesced.
// ---------------------------------------------------------------------------
__global__ __launch_bounds__(256) void ece_main(const float* __restrict__ outs,
                                                const int* __restrict__ labels,
                                                float* __restrict__ slots,
                                                int n_rows, int n_waves,
                                                int S, int priv) {
    __shared__ float s_hist[NVAL];

    const int tid = threadIdx.x;
    if (tid < NVAL) s_hist[tid] = 0.0f;
    __syncthreads();

    const int lane = tid & 63;
    const int sub  = lane & 7;    // chunk-column within the row
    const int rsub = lane >> 3;   // which of the wave's 8 rows
    const int gwave = blockIdx.x * 4 + (tid >> 6);

    const f32x4* __restrict__ outs4 = reinterpret_cast<const f32x4*>(outs);

    for (int rowBase = gwave * 8; rowBase < n_rows; rowBase += n_waves * 8) {
        const int row = rowBase + rsub;
        const bool live = (row < n_rows);

        int   lab = -1;
        float bestVal = -FLT_MAX;
        int   bestIdx = 0x7fffffff;

        if (live) {
            if (sub == 0) lab = labels[row];
            const f32x4* p = outs4 + (size_t)row * (C / 4) + sub;
            f32x4 v[4];
            #pragma unroll
            for (int j = 0; j < 4; ++j) v[j] = p[j * 8];

            // strict '>' serial scan in increasing element order
            // (element index of v[j].c = 4*sub + 32*j + c)
            const int b0 = 4 * sub;
            bestVal = v[0].x; bestIdx = b0;
            #pragma unroll
            for (int j = 0; j < 4; ++j) {
                const int b = b0 + 32 * j;
                if (j > 0 && v[j].x > bestVal) { bestVal = v[j].x; bestIdx = b; }
                if (v[j].y > bestVal) { bestVal = v[j].y; bestIdx = b + 1; }
                if (v[j].z > bestVal) { bestVal = v[j].z; bestIdx = b + 2; }
                if (v[j].w > bestVal) { bestVal = v[j].w; bestIdx = b + 3; }
            }
        }

        // 3-step butterfly within each 8-lane group (all 8 lanes share a row)
        #pragma unroll
        for (int m = 1; m <= 4; m <<= 1) {
            const float ov = __shfl_xor(bestVal, m);
            const int   oi = __shfl_xor(bestIdx, m);
            if (ov > bestVal || (ov == bestVal && oi < bestIdx)) {
                bestVal = ov;
                bestIdx = oi;
            }
        }

        if (sub == 0 && live) {
            // bin = clip(ceil(conf*20) - 1, 0, 19): same f32 arithmetic as ref
            int bin = (int)ceilf(bestVal * (float)N_BINS) - 1;
            bin = min(max(bin, 0), N_BINS - 1);
            atomicAdd(&s_hist[bin], bestVal);
            atomicAdd(&s_hist[N_BINS + bin], (bestIdx == lab) ? 1.0f : 0.0f);
        }
    }

    __syncthreads();
    if (tid < NVAL) {
        const int slot = blockIdx.x % S;   // == blockIdx.x in private mode
        if (priv) slots[(size_t)tid * S + slot] = s_hist[tid];
        else      atomicAdd(&slots[(size_t)tid * S + slot], s_hist[tid]);
    }
}

// ---------------------------------------------------------------------------
// Kernel 2: reduce S slots per value, then ece = sum_b |conf_b - acc_b| / N.
// One block, 1024 threads: 16 chunk-threads per value (64 value-groups,
// 40 active). Coalesced reads (consecutive threads -> consecutive slots),
// 4-accumulator unroll for load ILP. ~306 KB, L2-resident -> ~2 us.
// ---------------------------------------------------------------------------
__global__ __launch_bounds__(1024) void ece_final(const float* __restrict__ slots,
                                                  float* __restrict__ out,
                                                  int S, float inv_n) {
    __shared__ float red[NVAL][16];
    __shared__ float tot[NVAL];

    const int tid = threadIdx.x;
    const int j = tid >> 4;      // value index 0..63 (40 active)
    const int c = tid & 15;      // chunk within value

    if (j < NVAL) {
        const float* base = slots + (size_t)j * S;
        float p0 = 0.f, p1 = 0.f, p2 = 0.f, p3 = 0.f;
        int s = c;
        for (; s + 48 < S; s += 64) {
            p0 += base[s];
            p1 += base[s + 16];
            p2 += base[s + 32];
            p3 += base[s + 48];
        }
        for (; s < S; s += 16) p0 += base[s];
        red[j][c] = (p0 + p1) + (p2 + p3);
    }
    __syncthreads();

    if (tid < NVAL) {
        float t2 = 0.f;
        #pragma unroll
        for (int k = 0; k < 16; ++k) t2 += red[tid][k];
        tot[tid] = t2;
    }
    __syncthreads();

    if (tid < 64) {
        float d = (tid < N_BINS) ? fabsf(tot[tid] - tot[tid + N_BINS]) : 0.0f;
        #pragma unroll
        for (int m = 1; m <= 32; m <<= 1) d += __shfl_xor(d, m);
        if (tid == 0) out[0] = d * inv_n;
    }
}

extern "C" void kernel_launch(void* const* d_in, const int* in_sizes, int n_in,
                              void* d_out, int out_size, void* d_ws, size_t ws_size,
                              hipStream_t stream) {
    const float* outs   = (const float*)d_in[0];
    const int*   labels = (const int*)d_in[1];
    float*       out    = (float*)d_out;
    float*       slots  = (float*)d_ws;

    const int n_rows = in_sizes[1];    // labels count == N
    // 1954 blocks x 4 waves x 8 rows = 62528 rows/sweep; 1e6/62528 = 15.99
    // -> last grid-stride sweep is 99.3% full (vs 26% at 2048 blocks).
    const int blocks  = 1954;
    const int n_waves = blocks * 4;

    int S, priv;
    if (ws_size >= (size_t)blocks * NVAL * sizeof(float)) {
        S = blocks; priv = 1;          // block-private slots, plain stores
    } else {
        priv = 0;                      // shared slots + atomics (+ init)
        S = 1;
        while ((size_t)(S * 2) * NVAL * sizeof(float) <= ws_size && S * 2 < blocks)
            S <<= 1;
    }

    if (!priv) {
        const int total = S * NVAL;
        hipLaunchKernelGGL(ece_init, dim3((total + 255) / 256), dim3(256), 0,
                           stream, slots, total);
    }
    hipLaunchKernelGGL(ece_main, dim3(blocks), dim3(256), 0, stream,
                       outs, labels, slots, n_rows, n_waves, S, priv);
    hipLaunchKernelGGL(ece_final, dim3(1), dim3(1024), 0, stream,
                       slots, out, S, 1.0f / (float)n_rows);
}